// Round 3
// baseline (65.256 us; speedup 1.0000x reference)
//
#include <hip/hip_runtime.h>
#include <math.h>

#define HH 4
#define DD 64
#define BS 32

__device__ __forceinline__ float silu_f(float x) {
    return x / (1.0f + __expf(-x));
}

// Kernel A: per-compressed-block mean of k and v.
__global__ void hstu_cmp_means(const float* __restrict__ k, const float* __restrict__ v,
                               const int* __restrict__ offsets, int B,
                               float* __restrict__ k_cmp, float* __restrict__ v_cmp) {
    int c = blockIdx.x;
    int acc = 0, b = -1, jc = 0;
    for (int bb = 0; bb < B; ++bb) {
        int len = offsets[bb + 1] - offsets[bb];
        int nb = (len + BS - 1) >> 5;
        if (b < 0 && c < acc + nb) { b = bb; jc = c - acc; }
        acc += nb;
    }
    if (b < 0) return;
    int t0 = offsets[b] + jc * BS;
    int cnt = offsets[b + 1] - t0;
    if (cnt > BS) cnt = BS;

    int hd = threadIdx.x;
    const float* kp = k + (size_t)t0 * (HH * DD) + hd;
    const float* vp = v + (size_t)t0 * (HH * DD) + hd;
    float ks = 0.f, vs = 0.f;
    if (cnt == BS) {
        #pragma unroll
        for (int i = 0; i < BS; ++i) { ks += kp[i * (HH * DD)]; vs += vp[i * (HH * DD)]; }
    } else {
        for (int i = 0; i < cnt; ++i) { ks += kp[i * (HH * DD)]; vs += vp[i * (HH * DD)]; }
    }
    float inv = 1.0f / (float)cnt;
    k_cmp[(size_t)c * (HH * DD) + hd] = ks * inv;
    v_cmp[(size_t)c * (HH * DD) + hd] = vs * inv;
}

// Kernel B: one block per token t; 8 waves = (h in 0..3, half in 0..1).
// half splits o_cmp (8 cmp-blocks each) and o_slc (2 selected blocks each).
__global__ __launch_bounds__(512) void hstu_main(
    const float* __restrict__ q, const float* __restrict__ k, const float* __restrict__ v,
    const float* __restrict__ g_cmp, const float* __restrict__ g_slc,
    const int* __restrict__ offsets, int B,
    const float* __restrict__ k_cmp, const float* __restrict__ v_cmp,
    float* __restrict__ o_cmp, float* __restrict__ o_slc) {
    int t = blockIdx.x;
    int w = threadIdx.x >> 6;
    int h = w & 3;
    int half = w >> 2;
    int lane = threadIdx.x & 63;

    __shared__ __align__(16) float q_s[HH][DD];
    __shared__ float p_lds[HH][4][BS];
    __shared__ float cmp_part[HH][DD];
    __shared__ __align__(16) float slc_part[HH][16][4];

    // batch search + compressed-block bases
    int b = 0;
    while (b + 1 < B && t >= offsets[b + 1]) ++b;
    int seq_start = offsets[b];
    int p = t - seq_start;
    int q_blk = p >> 5;
    int base_cmp = 0, totC = 0;
    for (int bb = 0; bb < B; ++bb) {
        int nb = (offsets[bb + 1] - offsets[bb] + BS - 1) >> 5;
        if (bb < b) base_cmp += nb;
        totC += nb;
    }

    // q row into LDS — each wave writes its own full row (benign duplicate w/ other half)
    q_s[h][lane] = q[((size_t)t * HH + h) * DD + lane];
    __builtin_amdgcn_wave_barrier();

    // ---- Phase A: compressed-block scores (redundant in both halves) ----
    int j = lane >> 2, g4 = lane & 3;
    int cidx = base_cmp + j; if (cidx > totC - 1) cidx = totC - 1;  // safe addr; masked later
    float part = 0.f;
    {
        const float4* kr = (const float4*)(k_cmp + (size_t)cidx * (HH * DD) + h * DD + g4 * 16);
        const float4* qv = (const float4*)(&q_s[h][g4 * 16]);
        #pragma unroll
        for (int x = 0; x < 4; ++x) {
            float4 kk = kr[x]; float4 qq = qv[x];
            part += qq.x * kk.x + qq.y * kk.y + qq.z * kk.z + qq.w * kk.w;
        }
    }
    part += __shfl_xor(part, 1);
    part += __shfl_xor(part, 2);
    float s_own = part * 0.125f;
    float p_own = (j <= q_blk) ? silu_f(s_own) : 0.f;

    float sc_[16], pc_[16];
    #pragma unroll
    for (int jj = 0; jj < 16; ++jj) {
        sc_[jj] = __shfl(s_own, jj << 2);
        pc_[jj] = __shfl(p_own, jj << 2);
    }

    // ---- top-4 membership via rank + ballot (ties -> lowest index) ----
    int rank = 0;
    #pragma unroll
    for (int kk = 0; kk < 16; ++kk) {
        bool beats = (kk <= q_blk) && ((sc_[kk] > s_own) || (sc_[kk] == s_own && kk < j));
        rank += beats ? 1 : 0;
    }
    bool mine = (g4 == 0) && (j <= q_blk) && (rank < 4);
    unsigned long long msk = __ballot(mine);
    int sels[4];
    #pragma unroll
    for (int r = 0; r < 4; ++r) {
        sels[r] = msk ? (int)(__builtin_ctzll(msk) >> 2) : -1;
        msk &= msk - 1;
    }

    // ---- Phase B: o_cmp partial (half's 8 blocks). pc_=0 for non-causal -> no guard ----
    float acc = 0.f;
    #pragma unroll
    for (int m = 0; m < 8; ++m) {
        int jj = half * 8 + m;
        int ci = base_cmp + jj; if (ci > totC - 1) ci = totC - 1;
        acc += pc_[jj] * v_cmp[(size_t)ci * (HH * DD) + h * DD + lane];
    }

    // ---- Phase C: o_slc, 2 selected blocks per half ----
    int gh = lane >> 5, i32 = lane & 31;
    int tg = lane >> 4, dg = lane & 15;
    const float4* qh = (const float4*)(&q_s[h][gh * 32]);
    int r0 = half * 2, r1 = r0 + 1;
    int s0_ = sels[r0], s1_ = sels[r1];
    int lim0 = (s0_ >= 0) ? min(p - s0_ * BS + 1, BS) : 0;
    int lim1 = (s1_ >= 0) ? min(p - s1_ * BS + 1, BS) : 0;

    // QK for both blocks (independent load streams)
    float pt0 = 0.f, pt1 = 0.f;
    if (i32 < lim0) {
        const float4* kr = (const float4*)(k + ((size_t)(seq_start + s0_ * BS + i32) * HH + h) * DD + gh * 32);
        #pragma unroll
        for (int x = 0; x < 8; ++x) {
            float4 kk = kr[x]; float4 qq = qh[x];
            pt0 += qq.x * kk.x + qq.y * kk.y + qq.z * kk.z + qq.w * kk.w;
        }
    }
    if (i32 < lim1) {
        const float4* kr = (const float4*)(k + ((size_t)(seq_start + s1_ * BS + i32) * HH + h) * DD + gh * 32);
        #pragma unroll
        for (int x = 0; x < 8; ++x) {
            float4 kk = kr[x]; float4 qq = qh[x];
            pt1 += qq.x * kk.x + qq.y * kk.y + qq.z * kk.z + qq.w * kk.w;
        }
    }
    pt0 += __shfl_xor(pt0, 32);
    pt1 += __shfl_xor(pt1, 32);
    float ps0 = (i32 < lim0) ? silu_f(pt0 * 0.125f) : 0.f;
    float ps1 = (i32 < lim1) ? silu_f(pt1 * 0.125f) : 0.f;
    if (lane < BS) { p_lds[h][r0][lane] = ps0; p_lds[h][r1][lane] = ps1; }
    __builtin_amdgcn_wave_barrier();

    // PV for both blocks, interleaved
    float4 acc2 = make_float4(0.f, 0.f, 0.f, 0.f);
    #pragma unroll
    for (int m = 0; m < 8; ++m) {
        int it = m * 4 + tg;
        if (it < lim0) {
            float pv = p_lds[h][r0][it];
            float4 vv = *(const float4*)(v + ((size_t)(seq_start + s0_ * BS + it) * HH + h) * DD + dg * 4);
            acc2.x += pv * vv.x; acc2.y += pv * vv.y; acc2.z += pv * vv.z; acc2.w += pv * vv.w;
        }
        if (it < lim1) {
            float pv = p_lds[h][r1][it];
            float4 vv = *(const float4*)(v + ((size_t)(seq_start + s1_ * BS + it) * HH + h) * DD + dg * 4);
            acc2.x += pv * vv.x; acc2.y += pv * vv.y; acc2.z += pv * vv.z; acc2.w += pv * vv.w;
        }
    }
    acc2.x += __shfl_xor(acc2.x, 16); acc2.x += __shfl_xor(acc2.x, 32);
    acc2.y += __shfl_xor(acc2.y, 16); acc2.y += __shfl_xor(acc2.y, 32);
    acc2.z += __shfl_xor(acc2.z, 16); acc2.z += __shfl_xor(acc2.z, 32);
    acc2.w += __shfl_xor(acc2.w, 16); acc2.w += __shfl_xor(acc2.w, 32);

    // ---- combine halves ----
    if (half == 1) {
        cmp_part[h][lane] = acc;
        if (tg == 0) *(float4*)&slc_part[h][dg][0] = acc2;
    }
    __syncthreads();
    if (half == 0) {
        float gc = g_cmp[(size_t)t * HH + h];
        float o = (acc + cmp_part[h][lane]) * gc;
        o_cmp[((size_t)t * HH + h) * DD + lane] = o;
        if (tg == 0) {
            float4 other = *(const float4*)&slc_part[h][dg][0];
            float gs = g_slc[(size_t)t * HH + h];
            float4 oo = make_float4((acc2.x + other.x) * gs, (acc2.y + other.y) * gs,
                                    (acc2.z + other.z) * gs, (acc2.w + other.w) * gs);
            *(float4*)(o_slc + ((size_t)t * HH + h) * DD + dg * 4) = oo;
        }
    }
}

extern "C" void kernel_launch(void* const* d_in, const int* in_sizes, int n_in,
                              void* d_out, int out_size, void* d_ws, size_t ws_size,
                              hipStream_t stream) {
    const float* q     = (const float*)d_in[0];
    const float* k     = (const float*)d_in[1];
    const float* v     = (const float*)d_in[2];
    const float* g_cmp = (const float*)d_in[3];
    const float* g_slc = (const float*)d_in[4];
    const int*   offs  = (const int*)d_in[5];

    int T = in_sizes[0] / (HH * DD);
    int B = in_sizes[5] - 1;
    int maxC = (T + BS - 1) / BS + B;

    float* k_cmp = (float*)d_ws;
    float* v_cmp = (float*)d_ws + (size_t)maxC * HH * DD;
    float* o_cmp = (float*)d_out;
    float* o_slc = (float*)d_out + (size_t)T * HH * DD;

    hipLaunchKernelGGL(hstu_cmp_means, dim3(maxC), dim3(256), 0, stream,
                       k, v, offs, B, k_cmp, v_cmp);
    hipLaunchKernelGGL(hstu_main, dim3(T), dim3(512), 0, stream,
                       q, k, v, g_cmp, g_slc, offs, B, k_cmp, v_cmp, o_cmp, o_slc);
}

// Round 4
// 58.148 us; speedup vs baseline: 1.1222x; 1.1222x over previous
//
#include <hip/hip_runtime.h>
#include <math.h>

#define HH 4
#define DD 64
#define BS 32

__device__ __forceinline__ float silu_f(float x) {
    return x / (1.0f + __expf(-x));
}

// Kernel A: per-compressed-block mean of k and v.
__global__ void hstu_cmp_means(const float* __restrict__ k, const float* __restrict__ v,
                               const int* __restrict__ offsets, int B,
                               float* __restrict__ k_cmp, float* __restrict__ v_cmp) {
    int c = blockIdx.x;
    int acc = 0, b = -1, jc = 0;
    for (int bb = 0; bb < B; ++bb) {
        int len = offsets[bb + 1] - offsets[bb];
        int nb = (len + BS - 1) >> 5;
        if (b < 0 && c < acc + nb) { b = bb; jc = c - acc; }
        acc += nb;
    }
    if (b < 0) return;
    int t0 = offsets[b] + jc * BS;
    int cnt = offsets[b + 1] - t0;
    if (cnt > BS) cnt = BS;

    int hd = threadIdx.x;
    const float* kp = k + (size_t)t0 * (HH * DD) + hd;
    const float* vp = v + (size_t)t0 * (HH * DD) + hd;
    float ks = 0.f, vs = 0.f;
    if (cnt == BS) {
        #pragma unroll
        for (int i = 0; i < BS; ++i) { ks += kp[i * (HH * DD)]; vs += vp[i * (HH * DD)]; }
    } else {
        for (int i = 0; i < cnt; ++i) { ks += kp[i * (HH * DD)]; vs += vp[i * (HH * DD)]; }
    }
    float inv = 1.0f / (float)cnt;
    k_cmp[(size_t)c * (HH * DD) + hd] = ks * inv;
    v_cmp[(size_t)c * (HH * DD) + hd] = vs * inv;
}

// Kernel B1: scores + top-4 selection + o_cmp. grid = T, 4 waves = 4 heads.
__global__ __launch_bounds__(256) void hstu_cmp_top(
    const float* __restrict__ q, const float* __restrict__ g_cmp,
    const int* __restrict__ offsets, int B,
    const float* __restrict__ k_cmp, const float* __restrict__ v_cmp,
    float* __restrict__ o_cmp, int* __restrict__ sels_out) {
    int t = blockIdx.x;
    int h = threadIdx.x >> 6;
    int lane = threadIdx.x & 63;
    __shared__ __align__(16) float s_lds[HH][16];
    __shared__ __align__(16) float p_lds[HH][16];

    int b = 0;
    while (b + 1 < B && t >= offsets[b + 1]) ++b;
    int p = t - offsets[b];
    int q_blk = p >> 5;
    int base_cmp = 0, totC = 0;
    for (int bb = 0; bb < B; ++bb) {
        int nb = (offsets[bb + 1] - offsets[bb] + BS - 1) >> 5;
        if (bb < b) base_cmp += nb;
        totC += nb;
    }

    // ---- scores: lane=(j,g4), q loaded direct from global (L1 broadcast) ----
    int j = lane >> 2, g4 = lane & 3;
    int cidx = base_cmp + j; if (cidx > totC - 1) cidx = totC - 1;
    float part = 0.f;
    {
        const float4* qv = (const float4*)(q + ((size_t)t * HH + h) * DD + g4 * 16);
        const float4* kr = (const float4*)(k_cmp + (size_t)cidx * (HH * DD) + h * DD + g4 * 16);
        #pragma unroll
        for (int x = 0; x < 4; ++x) {
            float4 a = qv[x], kk = kr[x];
            part += a.x * kk.x + a.y * kk.y + a.z * kk.z + a.w * kk.w;
        }
    }
    part += __shfl_xor(part, 1);
    part += __shfl_xor(part, 2);
    float s_own = part * 0.125f;
    float p_own = (j <= q_blk) ? silu_f(s_own) : 0.f;
    if (g4 == 0) { s_lds[h][j] = s_own; p_lds[h][j] = p_own; }
    __builtin_amdgcn_wave_barrier();  // same-wave DS write->read ordering

    float sc_[16], pc_[16];
    #pragma unroll
    for (int x = 0; x < 4; ++x) {
        float4 sd = ((const float4*)s_lds[h])[x];
        float4 pd = ((const float4*)p_lds[h])[x];
        sc_[x*4+0] = sd.x; sc_[x*4+1] = sd.y; sc_[x*4+2] = sd.z; sc_[x*4+3] = sd.w;
        pc_[x*4+0] = pd.x; pc_[x*4+1] = pd.y; pc_[x*4+2] = pd.z; pc_[x*4+3] = pd.w;
    }

    // ---- top-4 via rank + ballot (ties -> lowest index; set-equal to lax.top_k) ----
    int rank = 0;
    #pragma unroll
    for (int kk = 0; kk < 16; ++kk) {
        bool beats = (kk <= q_blk) && ((sc_[kk] > s_own) || (sc_[kk] == s_own && kk < j));
        rank += beats ? 1 : 0;
    }
    bool mine = (g4 == 0) && (j <= q_blk) && (rank < 4);
    unsigned long long msk = __ballot(mine);
    int sel0, sel1, sel2, sel3;
    sel0 = msk ? (int)(__builtin_ctzll(msk) >> 2) : -1; msk &= msk - 1;
    sel1 = msk ? (int)(__builtin_ctzll(msk) >> 2) : -1; msk &= msk - 1;
    sel2 = msk ? (int)(__builtin_ctzll(msk) >> 2) : -1; msk &= msk - 1;
    sel3 = msk ? (int)(__builtin_ctzll(msk) >> 2) : -1;
    if (lane == 0) {
        int4 o4 = make_int4(sel0, sel1, sel2, sel3);
        *(int4*)(sels_out + ((size_t)t * HH + h) * 4) = o4;
    }

    // ---- o_cmp: lane = d; pc_=0 masks non-causal; clamped addresses ----
    float acc = 0.f;
    #pragma unroll
    for (int jj = 0; jj < 16; ++jj) {
        int ci = base_cmp + jj; if (ci > totC - 1) ci = totC - 1;
        acc += pc_[jj] * v_cmp[(size_t)ci * (HH * DD) + h * DD + lane];
    }
    acc *= g_cmp[(size_t)t * HH + h];
    o_cmp[((size_t)t * HH + h) * DD + lane] = acc;
}

// Kernel B2: o_slc. grid = T*HH, 4 waves = 4 selected blocks.
__global__ __launch_bounds__(256) void hstu_slc(
    const float* __restrict__ q, const float* __restrict__ k, const float* __restrict__ v,
    const float* __restrict__ g_slc, const int* __restrict__ offsets, int B,
    const int* __restrict__ sels_in, float* __restrict__ o_slc) {
    int t = blockIdx.x >> 2, h = blockIdx.x & 3;
    int r = threadIdx.x >> 6;
    int lane = threadIdx.x & 63;
    __shared__ float p_s[4][BS];
    __shared__ float acc_s[4][DD];

    int b = 0;
    while (b + 1 < B && t >= offsets[b + 1]) ++b;
    int seq_start = offsets[b];
    int p = t - seq_start;

    int4 s4 = *(const int4*)(sels_in + ((size_t)t * HH + h) * 4);
    int sel = (r == 0) ? s4.x : (r == 1) ? s4.y : (r == 2) ? s4.z : s4.w;
    int lim = (sel >= 0) ? min(p - sel * BS + 1, BS) : 0;  // >=1 when sel>=0

    // ---- QK: lane=(gh,i32); unconditional loads with clamped row ----
    int gh = lane >> 5, i32 = lane & 31;
    int rowk = t;
    if (sel >= 0) rowk = seq_start + sel * BS + min(i32, lim - 1);
    float pt = 0.f;
    {
        const float4* qv = (const float4*)(q + ((size_t)t * HH + h) * DD + gh * 32);
        const float4* kr = (const float4*)(k + ((size_t)rowk * HH + h) * DD + gh * 32);
        #pragma unroll
        for (int x = 0; x < 8; ++x) {
            float4 a = qv[x], kk = kr[x];
            pt += a.x * kk.x + a.y * kk.y + a.z * kk.z + a.w * kk.w;
        }
    }
    pt += __shfl_xor(pt, 32);
    float ps = (i32 < lim) ? silu_f(pt * 0.125f) : 0.f;
    if (lane < BS) p_s[r][lane] = ps;
    __builtin_amdgcn_wave_barrier();  // same-wave DS ordering

    // ---- PV: lane = d; 32 fully-unrolled independent iterations ----
    float acc = 0.f;
    #pragma unroll
    for (int it = 0; it < BS; ++it) {
        int rowv = t;
        if (sel >= 0) rowv = seq_start + sel * BS + min(it, lim - 1);
        // p_s is 0 for it>=lim, so the clamped row contributes nothing
        acc += p_s[r][it] * v[((size_t)rowv * HH + h) * DD + lane];
    }

    // ---- combine 4 waves ----
    if (r != 0) acc_s[r][lane] = acc;
    __syncthreads();
    if (r == 0) {
        float o = acc + acc_s[1][lane] + acc_s[2][lane] + acc_s[3][lane];
        o *= g_slc[(size_t)t * HH + h];
        o_slc[((size_t)t * HH + h) * DD + lane] = o;
    }
}

extern "C" void kernel_launch(void* const* d_in, const int* in_sizes, int n_in,
                              void* d_out, int out_size, void* d_ws, size_t ws_size,
                              hipStream_t stream) {
    const float* q     = (const float*)d_in[0];
    const float* k     = (const float*)d_in[1];
    const float* v     = (const float*)d_in[2];
    const float* g_cmp = (const float*)d_in[3];
    const float* g_slc = (const float*)d_in[4];
    const int*   offs  = (const int*)d_in[5];

    int T = in_sizes[0] / (HH * DD);
    int B = in_sizes[5] - 1;
    int maxC = (T + BS - 1) / BS + B;

    float* k_cmp = (float*)d_ws;
    float* v_cmp = (float*)d_ws + (size_t)maxC * HH * DD;
    int*   sels  = (int*)(v_cmp + (size_t)maxC * HH * DD);
    float* o_cmp = (float*)d_out;
    float* o_slc = (float*)d_out + (size_t)T * HH * DD;

    hipLaunchKernelGGL(hstu_cmp_means, dim3(maxC), dim3(256), 0, stream,
                       k, v, offs, B, k_cmp, v_cmp);
    hipLaunchKernelGGL(hstu_cmp_top, dim3(T), dim3(256), 0, stream,
                       q, g_cmp, offs, B, k_cmp, v_cmp, o_cmp, sels);
    hipLaunchKernelGGL(hstu_slc, dim3(T * HH), dim3(256), 0, stream,
                       q, k, v, g_slc, offs, B, sels, o_slc);
}

// Round 5
// 44.971 us; speedup vs baseline: 1.4511x; 1.2930x over previous
//
#include <hip/hip_runtime.h>
#include <math.h>

#define HH 4
#define DD 64
#define BS 32

__device__ __forceinline__ float silu_f(float x) {
    return x / (1.0f + __expf(-x));
}

// Kernel A: per-compressed-block mean of k and v.
__global__ void hstu_cmp_means(const float* __restrict__ k, const float* __restrict__ v,
                               const int* __restrict__ offsets, int B,
                               float* __restrict__ k_cmp, float* __restrict__ v_cmp) {
    int c = blockIdx.x;
    int acc = 0, b = -1, jc = 0;
    for (int bb = 0; bb < B; ++bb) {
        int len = offsets[bb + 1] - offsets[bb];
        int nb = (len + BS - 1) >> 5;
        if (b < 0 && c < acc + nb) { b = bb; jc = c - acc; }
        acc += nb;
    }
    if (b < 0) return;
    int t0 = offsets[b] + jc * BS;
    int cnt = offsets[b + 1] - t0;
    if (cnt > BS) cnt = BS;

    int hd = threadIdx.x;
    const float* kp = k + (size_t)t0 * (HH * DD) + hd;
    const float* vp = v + (size_t)t0 * (HH * DD) + hd;
    float ks = 0.f, vs = 0.f;
    if (cnt == BS) {
        #pragma unroll
        for (int i = 0; i < BS; ++i) { ks += kp[i * (HH * DD)]; vs += vp[i * (HH * DD)]; }
    } else {
        for (int i = 0; i < cnt; ++i) { ks += kp[i * (HH * DD)]; vs += vp[i * (HH * DD)]; }
    }
    float inv = 1.0f / (float)cnt;
    k_cmp[(size_t)c * (HH * DD) + hd] = ks * inv;
    v_cmp[(size_t)c * (HH * DD) + hd] = vs * inv;
}

// Kernel B1: scores + top-4 selection + o_cmp. grid = T, 4 waves = 4 heads.
__global__ __launch_bounds__(256) void hstu_cmp_top(
    const float* __restrict__ q, const float* __restrict__ g_cmp,
    const int* __restrict__ offsets, int B,
    const float* __restrict__ k_cmp, const float* __restrict__ v_cmp,
    float* __restrict__ o_cmp, int* __restrict__ sels_out) {
    int t = blockIdx.x;
    int h = threadIdx.x >> 6;
    int lane = threadIdx.x & 63;
    __shared__ __align__(16) float s_lds[HH][16];
    __shared__ __align__(16) float p_lds[HH][16];

    int b = 0;
    while (b + 1 < B && t >= offsets[b + 1]) ++b;
    int p = t - offsets[b];
    int q_blk = p >> 5;
    int base_cmp = 0, totC = 0;
    for (int bb = 0; bb < B; ++bb) {
        int nb = (offsets[bb + 1] - offsets[bb] + BS - 1) >> 5;
        if (bb < b) base_cmp += nb;
        totC += nb;
    }

    // ---- scores, sector-coalesced: lane=(c4,d4); instr covers 4 rows x 256B ----
    int d4 = lane & 15, c4 = lane >> 4;
    float4 qf = *(const float4*)(q + ((size_t)t * HH + h) * DD + d4 * 4);
    float sc_own[4], pc_own[4];
    #pragma unroll
    for (int m = 0; m < 4; ++m) {
        int j = m * 4 + c4;
        int ci = base_cmp + j; if (ci > totC - 1) ci = totC - 1;
        float4 kk = *(const float4*)(k_cmp + (size_t)ci * (HH * DD) + h * DD + d4 * 4);
        float pp = qf.x * kk.x + qf.y * kk.y + qf.z * kk.z + qf.w * kk.w;
        pp += __shfl_xor(pp, 1);
        pp += __shfl_xor(pp, 2);
        pp += __shfl_xor(pp, 4);
        pp += __shfl_xor(pp, 8);
        sc_own[m] = pp * 0.125f;
        pc_own[m] = (j <= q_blk) ? silu_f(sc_own[m]) : 0.f;
    }
    if (d4 == 0) {
        #pragma unroll
        for (int m = 0; m < 4; ++m) {
            s_lds[h][m * 4 + c4] = sc_own[m];
            p_lds[h][m * 4 + c4] = pc_own[m];
        }
    }
    __builtin_amdgcn_wave_barrier();  // same-wave DS write->read ordering

    float sc_[16], pc_[16];
    #pragma unroll
    for (int x = 0; x < 4; ++x) {
        float4 sd = ((const float4*)s_lds[h])[x];
        float4 pd = ((const float4*)p_lds[h])[x];
        sc_[x*4+0] = sd.x; sc_[x*4+1] = sd.y; sc_[x*4+2] = sd.z; sc_[x*4+3] = sd.w;
        pc_[x*4+0] = pd.x; pc_[x*4+1] = pd.y; pc_[x*4+2] = pd.z; pc_[x*4+3] = pd.w;
    }

    // ---- top-4 via rank + ballot (ties -> lowest index; set-equal to lax.top_k) ----
    int j_own = lane >> 2;
    float s_own = sc_[j_own];
    int rank = 0;
    #pragma unroll
    for (int kk = 0; kk < 16; ++kk) {
        bool beats = (kk <= q_blk) && ((sc_[kk] > s_own) || (sc_[kk] == s_own && kk < j_own));
        rank += beats ? 1 : 0;
    }
    bool mine = ((lane & 3) == 0) && (j_own <= q_blk) && (rank < 4);
    unsigned long long msk = __ballot(mine);
    int sel0, sel1, sel2, sel3;
    sel0 = msk ? (int)(__builtin_ctzll(msk) >> 2) : -1; msk &= msk - 1;
    sel1 = msk ? (int)(__builtin_ctzll(msk) >> 2) : -1; msk &= msk - 1;
    sel2 = msk ? (int)(__builtin_ctzll(msk) >> 2) : -1; msk &= msk - 1;
    sel3 = msk ? (int)(__builtin_ctzll(msk) >> 2) : -1;
    if (lane == 0) {
        int4 o4 = make_int4(sel0, sel1, sel2, sel3);
        *(int4*)(sels_out + ((size_t)t * HH + h) * 4) = o4;
    }

    // ---- o_cmp: lane = d; pc_=0 masks non-causal; clamped addresses ----
    float acc = 0.f;
    #pragma unroll
    for (int jj = 0; jj < 16; ++jj) {
        int ci = base_cmp + jj; if (ci > totC - 1) ci = totC - 1;
        acc += pc_[jj] * v_cmp[(size_t)ci * (HH * DD) + h * DD + lane];
    }
    acc *= g_cmp[(size_t)t * HH + h];
    o_cmp[((size_t)t * HH + h) * DD + lane] = acc;
}

// Kernel B2: o_slc. grid = T*HH, 4 waves = 4 selected blocks.
__global__ __launch_bounds__(256) void hstu_slc(
    const float* __restrict__ q, const float* __restrict__ k, const float* __restrict__ v,
    const float* __restrict__ g_slc, const int* __restrict__ offsets, int B,
    const int* __restrict__ sels_in, float* __restrict__ o_slc) {
    int t = blockIdx.x >> 2, h = blockIdx.x & 3;
    int r = threadIdx.x >> 6;
    int lane = threadIdx.x & 63;
    __shared__ float p_s[4][BS];
    __shared__ float acc_s[4][DD];

    int b = 0;
    while (b + 1 < B && t >= offsets[b + 1]) ++b;
    int seq_start = offsets[b];
    int p = t - seq_start;

    int4 s4 = *(const int4*)(sels_in + ((size_t)t * HH + h) * 4);
    int sel = (r == 0) ? s4.x : (r == 1) ? s4.y : (r == 2) ? s4.z : s4.w;
    int lim = (sel >= 0) ? min(p - sel * BS + 1, BS) : 0;  // >=1 when sel>=0
    int blk_base = seq_start + sel * BS;

    // ---- QK, sector-coalesced: lane=(it4,d4); instr covers 4 rows x 256B ----
    int d4 = lane & 15, it4 = lane >> 4;
    float4 qf = *(const float4*)(q + ((size_t)t * HH + h) * DD + d4 * 4);
    float ps_own[8];
    #pragma unroll
    for (int m = 0; m < 8; ++m) {
        int i = m * 4 + it4;
        int row = t;
        if (sel >= 0) row = blk_base + min(i, lim - 1);
        float4 kk = *(const float4*)(k + ((size_t)row * HH + h) * DD + d4 * 4);
        float pp = qf.x * kk.x + qf.y * kk.y + qf.z * kk.z + qf.w * kk.w;
        pp += __shfl_xor(pp, 1);
        pp += __shfl_xor(pp, 2);
        pp += __shfl_xor(pp, 4);
        pp += __shfl_xor(pp, 8);
        ps_own[m] = (i < lim) ? silu_f(pp * 0.125f) : 0.f;
    }
    if (d4 == 0) {
        #pragma unroll
        for (int m = 0; m < 8; ++m) p_s[r][m * 4 + it4] = ps_own[m];
    }
    __builtin_amdgcn_wave_barrier();  // same-wave DS ordering

    // ---- PV: lane = d; 32 fully-unrolled coalesced rows ----
    float acc = 0.f;
    #pragma unroll
    for (int it = 0; it < BS; ++it) {
        int rowv = t;
        if (sel >= 0) rowv = blk_base + min(it, lim - 1);
        // p_s is 0 for it>=lim, so the clamped row contributes nothing
        acc += p_s[r][it] * v[((size_t)rowv * HH + h) * DD + lane];
    }

    // ---- combine 4 waves ----
    if (r != 0) acc_s[r][lane] = acc;
    __syncthreads();
    if (r == 0) {
        float o = acc + acc_s[1][lane] + acc_s[2][lane] + acc_s[3][lane];
        o *= g_slc[(size_t)t * HH + h];
        o_slc[((size_t)t * HH + h) * DD + lane] = o;
    }
}

extern "C" void kernel_launch(void* const* d_in, const int* in_sizes, int n_in,
                              void* d_out, int out_size, void* d_ws, size_t ws_size,
                              hipStream_t stream) {
    const float* q     = (const float*)d_in[0];
    const float* k     = (const float*)d_in[1];
    const float* v     = (const float*)d_in[2];
    const float* g_cmp = (const float*)d_in[3];
    const float* g_slc = (const float*)d_in[4];
    const int*   offs  = (const int*)d_in[5];

    int T = in_sizes[0] / (HH * DD);
    int B = in_sizes[5] - 1;
    int maxC = (T + BS - 1) / BS + B;

    float* k_cmp = (float*)d_ws;
    float* v_cmp = (float*)d_ws + (size_t)maxC * HH * DD;
    int*   sels  = (int*)(v_cmp + (size_t)maxC * HH * DD);
    float* o_cmp = (float*)d_out;
    float* o_slc = (float*)d_out + (size_t)T * HH * DD;

    hipLaunchKernelGGL(hstu_cmp_means, dim3(maxC), dim3(256), 0, stream,
                       k, v, offs, B, k_cmp, v_cmp);
    hipLaunchKernelGGL(hstu_cmp_top, dim3(T), dim3(256), 0, stream,
                       q, g_cmp, offs, B, k_cmp, v_cmp, o_cmp, sels);
    hipLaunchKernelGGL(hstu_slc, dim3(T * HH), dim3(256), 0, stream,
                       q, k, v, g_slc, offs, B, sels, o_slc);
}

// Round 6
// 44.840 us; speedup vs baseline: 1.4553x; 1.0029x over previous
//
#include <hip/hip_runtime.h>
#include <math.h>

#define HH 4
#define DD 64
#define BS 32

__device__ __forceinline__ float silu_f(float x) {
    return x / (1.0f + __expf(-x));
}

// Kernel A: per-compressed-block mean of k and v.
// 256 thr = 4 row-groups x 64 lanes; each load instr covers one full 256-float row.
__global__ __launch_bounds__(256) void hstu_cmp_means(
    const float* __restrict__ k, const float* __restrict__ v,
    const int* __restrict__ offsets, int B,
    float* __restrict__ k_cmp, float* __restrict__ v_cmp) {
    int c = blockIdx.x;
    int acc = 0, b = -1, jc = 0;
    for (int bb = 0; bb < B; ++bb) {
        int len = offsets[bb + 1] - offsets[bb];
        int nb = (len + BS - 1) >> 5;
        if (b < 0 && c < acc + nb) { b = bb; jc = c - acc; }
        acc += nb;
    }
    if (b < 0) return;
    int t0 = offsets[b] + jc * BS;
    int cnt = offsets[b + 1] - t0;
    if (cnt > BS) cnt = BS;

    int rg = threadIdx.x >> 6;     // row-group 0..3 (8 rows each)
    int lane = threadIdx.x & 63;   // float4 chunk within the (h,d) row

    __shared__ __align__(16) float4 red_k[4][64];
    __shared__ __align__(16) float4 red_v[4][64];

    float4 ks = make_float4(0.f, 0.f, 0.f, 0.f);
    float4 vs = make_float4(0.f, 0.f, 0.f, 0.f);
    #pragma unroll
    for (int m = 0; m < 8; ++m) {
        int i = rg * 8 + m;                 // wave-uniform
        if (i < cnt) {
            const float4 kk = *(const float4*)(k + (size_t)(t0 + i) * (HH * DD) + lane * 4);
            const float4 vv = *(const float4*)(v + (size_t)(t0 + i) * (HH * DD) + lane * 4);
            ks.x += kk.x; ks.y += kk.y; ks.z += kk.z; ks.w += kk.w;
            vs.x += vv.x; vs.y += vv.y; vs.z += vv.z; vs.w += vv.w;
        }
    }
    red_k[rg][lane] = ks;
    red_v[rg][lane] = vs;
    __syncthreads();
    if (rg == 0) {
        float inv = 1.0f / (float)cnt;
        float4 a = ks, bv = vs;
        #pragma unroll
        for (int g = 1; g < 4; ++g) {
            float4 rk = red_k[g][lane], rv = red_v[g][lane];
            a.x += rk.x; a.y += rk.y; a.z += rk.z; a.w += rk.w;
            bv.x += rv.x; bv.y += rv.y; bv.z += rv.z; bv.w += rv.w;
        }
        a.x *= inv; a.y *= inv; a.z *= inv; a.w *= inv;
        bv.x *= inv; bv.y *= inv; bv.z *= inv; bv.w *= inv;
        *(float4*)(k_cmp + (size_t)c * (HH * DD) + lane * 4) = a;
        *(float4*)(v_cmp + (size_t)c * (HH * DD) + lane * 4) = bv;
    }
}

// Kernel B1: scores + top-4 selection + o_cmp. grid = T, 4 waves = 4 heads.
__global__ __launch_bounds__(256) void hstu_cmp_top(
    const float* __restrict__ q, const float* __restrict__ g_cmp,
    const int* __restrict__ offsets, int B,
    const float* __restrict__ k_cmp, const float* __restrict__ v_cmp,
    float* __restrict__ o_cmp, int* __restrict__ sels_out) {
    int t = blockIdx.x;
    int h = threadIdx.x >> 6;
    int lane = threadIdx.x & 63;
    __shared__ __align__(16) float s_lds[HH][16];
    __shared__ __align__(16) float p_lds[HH][16];

    int b = 0;
    while (b + 1 < B && t >= offsets[b + 1]) ++b;
    int p = t - offsets[b];
    int q_blk = p >> 5;
    int base_cmp = 0, totC = 0;
    for (int bb = 0; bb < B; ++bb) {
        int nb = (offsets[bb + 1] - offsets[bb] + BS - 1) >> 5;
        if (bb < b) base_cmp += nb;
        totC += nb;
    }

    // ---- scores: lane=(c4,d4); 4 k-load instrs ----
    int d4 = lane & 15, c4 = lane >> 4;
    float4 qf = *(const float4*)(q + ((size_t)t * HH + h) * DD + d4 * 4);
    float sc_own[4], pc_own[4];
    #pragma unroll
    for (int m = 0; m < 4; ++m) {
        int j = m * 4 + c4;
        int ci = base_cmp + j; if (ci > totC - 1) ci = totC - 1;
        float4 kk = *(const float4*)(k_cmp + (size_t)ci * (HH * DD) + h * DD + d4 * 4);
        float pp = qf.x * kk.x + qf.y * kk.y + qf.z * kk.z + qf.w * kk.w;
        pp += __shfl_xor(pp, 1);
        pp += __shfl_xor(pp, 2);
        pp += __shfl_xor(pp, 4);
        pp += __shfl_xor(pp, 8);
        sc_own[m] = pp * 0.125f;
        pc_own[m] = (j <= q_blk) ? silu_f(sc_own[m]) : 0.f;
    }
    if (d4 == 0) {
        #pragma unroll
        for (int m = 0; m < 4; ++m) {
            s_lds[h][m * 4 + c4] = sc_own[m];
            p_lds[h][m * 4 + c4] = pc_own[m];
        }
    }
    __builtin_amdgcn_wave_barrier();  // same-wave DS write->read ordering

    float sc_[16], pc_[16];
    #pragma unroll
    for (int x = 0; x < 4; ++x) {
        float4 sd = ((const float4*)s_lds[h])[x];
        float4 pd = ((const float4*)p_lds[h])[x];
        sc_[x*4+0] = sd.x; sc_[x*4+1] = sd.y; sc_[x*4+2] = sd.z; sc_[x*4+3] = sd.w;
        pc_[x*4+0] = pd.x; pc_[x*4+1] = pd.y; pc_[x*4+2] = pd.z; pc_[x*4+3] = pd.w;
    }

    // ---- top-4 via rank + ballot (ties -> lowest index; set-equal to lax.top_k) ----
    int j_own = lane >> 2;
    float s_own = sc_[j_own];
    int rank = 0;
    #pragma unroll
    for (int kk = 0; kk < 16; ++kk) {
        bool beats = (kk <= q_blk) && ((sc_[kk] > s_own) || (sc_[kk] == s_own && kk < j_own));
        rank += beats ? 1 : 0;
    }
    bool mine = ((lane & 3) == 0) && (j_own <= q_blk) && (rank < 4);
    unsigned long long msk = __ballot(mine);
    int sel0, sel1, sel2, sel3;
    sel0 = msk ? (int)(__builtin_ctzll(msk) >> 2) : -1; msk &= msk - 1;
    sel1 = msk ? (int)(__builtin_ctzll(msk) >> 2) : -1; msk &= msk - 1;
    sel2 = msk ? (int)(__builtin_ctzll(msk) >> 2) : -1; msk &= msk - 1;
    sel3 = msk ? (int)(__builtin_ctzll(msk) >> 2) : -1;
    if (lane == 0) {
        int4 o4 = make_int4(sel0, sel1, sel2, sel3);
        *(int4*)(sels_out + ((size_t)t * HH + h) * 4) = o4;
    }

    // ---- o_cmp: lane=(c4,d4); 4 v-load instrs + float4 shfl reduce over c4 ----
    float4 facc = make_float4(0.f, 0.f, 0.f, 0.f);
    #pragma unroll
    for (int m = 0; m < 4; ++m) {
        int j = m * 4 + c4;
        int ci = base_cmp + j; if (ci > totC - 1) ci = totC - 1;
        float4 vv = *(const float4*)(v_cmp + (size_t)ci * (HH * DD) + h * DD + d4 * 4);
        float pj = pc_[j];  // 0 for non-causal
        facc.x += pj * vv.x; facc.y += pj * vv.y; facc.z += pj * vv.z; facc.w += pj * vv.w;
    }
    facc.x += __shfl_xor(facc.x, 16); facc.x += __shfl_xor(facc.x, 32);
    facc.y += __shfl_xor(facc.y, 16); facc.y += __shfl_xor(facc.y, 32);
    facc.z += __shfl_xor(facc.z, 16); facc.z += __shfl_xor(facc.z, 32);
    facc.w += __shfl_xor(facc.w, 16); facc.w += __shfl_xor(facc.w, 32);
    if (c4 == 0) {
        float gc = g_cmp[(size_t)t * HH + h];
        float4 o = make_float4(facc.x * gc, facc.y * gc, facc.z * gc, facc.w * gc);
        *(float4*)(o_cmp + ((size_t)t * HH + h) * DD + d4 * 4) = o;
    }
}

// Kernel B2: o_slc. grid = T*HH, 4 waves = 4 selected blocks.
// lane=(it4,d4); k AND v rows in the same layout; each lane's prob stays
// lane-local after the 16-lane butterfly -> PV needs no LDS broadcast.
__global__ __launch_bounds__(256) void hstu_slc(
    const float* __restrict__ q, const float* __restrict__ k, const float* __restrict__ v,
    const float* __restrict__ g_slc, const int* __restrict__ offsets, int B,
    const int* __restrict__ sels_in, float* __restrict__ o_slc) {
    int t = blockIdx.x >> 2, h = blockIdx.x & 3;
    int r = threadIdx.x >> 6;
    int lane = threadIdx.x & 63;
    __shared__ __align__(16) float4 red_s[4][16];

    int b = 0;
    while (b + 1 < B && t >= offsets[b + 1]) ++b;
    int seq_start = offsets[b];
    int p = t - seq_start;

    int4 s4 = *(const int4*)(sels_in + ((size_t)t * HH + h) * 4);
    int sel = (r == 0) ? s4.x : (r == 1) ? s4.y : (r == 2) ? s4.z : s4.w;
    int lim = (sel >= 0) ? min(p - sel * BS + 1, BS) : 0;  // >=1 when sel>=0
    int blk_base = seq_start + sel * BS;

    int d4 = lane & 15, it4 = lane >> 4;
    float4 qf = *(const float4*)(q + ((size_t)t * HH + h) * DD + d4 * 4);

    // 8 k-row + 8 v-row loads, all independent and issued up front
    float4 kk[8], vv[8];
    int rows[8];
    #pragma unroll
    for (int m = 0; m < 8; ++m) {
        int i = m * 4 + it4;
        int row = t;
        if (sel >= 0) row = blk_base + min(i, lim - 1);
        rows[m] = row;
        kk[m] = *(const float4*)(k + ((size_t)row * HH + h) * DD + d4 * 4);
    }
    #pragma unroll
    for (int m = 0; m < 8; ++m)
        vv[m] = *(const float4*)(v + ((size_t)rows[m] * HH + h) * DD + d4 * 4);

    // scores -> probs (lane-local per row), then PV lane-locally
    float4 facc = make_float4(0.f, 0.f, 0.f, 0.f);
    #pragma unroll
    for (int m = 0; m < 8; ++m) {
        int i = m * 4 + it4;
        float pp = qf.x * kk[m].x + qf.y * kk[m].y + qf.z * kk[m].z + qf.w * kk[m].w;
        pp += __shfl_xor(pp, 1);
        pp += __shfl_xor(pp, 2);
        pp += __shfl_xor(pp, 4);
        pp += __shfl_xor(pp, 8);
        float ps = (i < lim) ? silu_f(pp * 0.125f) : 0.f;
        facc.x += ps * vv[m].x; facc.y += ps * vv[m].y;
        facc.z += ps * vv[m].z; facc.w += ps * vv[m].w;
    }

    // reduce over it4 groups (each float4 lane-slice covers d range d4*4..+4)
    facc.x += __shfl_xor(facc.x, 16); facc.x += __shfl_xor(facc.x, 32);
    facc.y += __shfl_xor(facc.y, 16); facc.y += __shfl_xor(facc.y, 32);
    facc.z += __shfl_xor(facc.z, 16); facc.z += __shfl_xor(facc.z, 32);
    facc.w += __shfl_xor(facc.w, 16); facc.w += __shfl_xor(facc.w, 32);

    // cross-wave combine
    if (r != 0 && it4 == 0) red_s[r][d4] = facc;
    __syncthreads();
    if (r == 0 && it4 == 0) {
        float4 o = facc;
        #pragma unroll
        for (int g = 1; g < 4; ++g) {
            float4 rr = red_s[g][d4];
            o.x += rr.x; o.y += rr.y; o.z += rr.z; o.w += rr.w;
        }
        float gs = g_slc[(size_t)t * HH + h];
        o.x *= gs; o.y *= gs; o.z *= gs; o.w *= gs;
        *(float4*)(o_slc + ((size_t)t * HH + h) * DD + d4 * 4) = o;
    }
}

extern "C" void kernel_launch(void* const* d_in, const int* in_sizes, int n_in,
                              void* d_out, int out_size, void* d_ws, size_t ws_size,
                              hipStream_t stream) {
    const float* q     = (const float*)d_in[0];
    const float* k     = (const float*)d_in[1];
    const float* v     = (const float*)d_in[2];
    const float* g_cmp = (const float*)d_in[3];
    const float* g_slc = (const float*)d_in[4];
    const int*   offs  = (const int*)d_in[5];

    int T = in_sizes[0] / (HH * DD);
    int B = in_sizes[5] - 1;
    int maxC = (T + BS - 1) / BS + B;

    float* k_cmp = (float*)d_ws;
    float* v_cmp = (float*)d_ws + (size_t)maxC * HH * DD;
    int*   sels  = (int*)(v_cmp + (size_t)maxC * HH * DD);
    float* o_cmp = (float*)d_out;
    float* o_slc = (float*)d_out + (size_t)T * HH * DD;

    hipLaunchKernelGGL(hstu_cmp_means, dim3(maxC), dim3(256), 0, stream,
                       k, v, offs, B, k_cmp, v_cmp);
    hipLaunchKernelGGL(hstu_cmp_top, dim3(T), dim3(256), 0, stream,
                       q, g_cmp, offs, B, k_cmp, v_cmp, o_cmp, sels);
    hipLaunchKernelGGL(hstu_slc, dim3(T * HH), dim3(256), 0, stream,
                       q, k, v, g_slc, offs, B, sels, o_slc);
}

// Round 7
// 36.259 us; speedup vs baseline: 1.7997x; 1.2366x over previous
//
#include <hip/hip_runtime.h>
#include <math.h>

#define HH 4
#define DD 64
#define BS 32

__device__ __forceinline__ float silu_f(float x) {
    return x / (1.0f + __expf(-x));
}

// f32 -> bf16 (RNE)
__device__ __forceinline__ unsigned short f2bf(float f) {
    unsigned u = __float_as_uint(f);
    unsigned r = (u + 0x7fffu + ((u >> 16) & 1u)) >> 16;
    return (unsigned short)r;
}
__device__ __forceinline__ float bflo(unsigned w) { return __uint_as_float(w << 16); }
__device__ __forceinline__ float bfhi(unsigned w) { return __uint_as_float(w & 0xffff0000u); }

// Kernel A: per-compressed-block mean of k and v + bf16 copies of k,v.
// Compressed blocks partition the token range, so every row is written once.
__global__ __launch_bounds__(256) void hstu_cmp_means(
    const float* __restrict__ k, const float* __restrict__ v,
    const int* __restrict__ offsets, int B,
    float* __restrict__ k_cmp, float* __restrict__ v_cmp,
    unsigned short* __restrict__ kb, unsigned short* __restrict__ vb) {
    int c = blockIdx.x;
    int acc = 0, b = -1, jc = 0;
    for (int bb = 0; bb < B; ++bb) {
        int len = offsets[bb + 1] - offsets[bb];
        int nb = (len + BS - 1) >> 5;
        if (b < 0 && c < acc + nb) { b = bb; jc = c - acc; }
        acc += nb;
    }
    if (b < 0) return;
    int t0 = offsets[b] + jc * BS;
    int cnt = offsets[b + 1] - t0;
    if (cnt > BS) cnt = BS;

    int rg = threadIdx.x >> 6;     // row-group 0..3 (8 rows each)
    int lane = threadIdx.x & 63;   // float4 chunk within the 256-float row

    __shared__ __align__(16) float4 red_k[4][64];
    __shared__ __align__(16) float4 red_v[4][64];

    float4 ks = make_float4(0.f, 0.f, 0.f, 0.f);
    float4 vs = make_float4(0.f, 0.f, 0.f, 0.f);
    #pragma unroll
    for (int m = 0; m < 8; ++m) {
        int i = rg * 8 + m;                 // wave-uniform guard
        if (i < cnt) {
            size_t off = (size_t)(t0 + i) * (HH * DD) + lane * 4;
            const float4 kk = *(const float4*)(k + off);
            const float4 vv = *(const float4*)(v + off);
            ks.x += kk.x; ks.y += kk.y; ks.z += kk.z; ks.w += kk.w;
            vs.x += vv.x; vs.y += vv.y; vs.z += vv.z; vs.w += vv.w;
            ushort4 kh, vh;
            kh.x = f2bf(kk.x); kh.y = f2bf(kk.y); kh.z = f2bf(kk.z); kh.w = f2bf(kk.w);
            vh.x = f2bf(vv.x); vh.y = f2bf(vv.y); vh.z = f2bf(vv.z); vh.w = f2bf(vv.w);
            *(ushort4*)(kb + off) = kh;
            *(ushort4*)(vb + off) = vh;
        }
    }
    red_k[rg][lane] = ks;
    red_v[rg][lane] = vs;
    __syncthreads();
    if (rg == 0) {
        float inv = 1.0f / (float)cnt;
        float4 a = ks, bv = vs;
        #pragma unroll
        for (int g = 1; g < 4; ++g) {
            float4 rk = red_k[g][lane], rv = red_v[g][lane];
            a.x += rk.x; a.y += rk.y; a.z += rk.z; a.w += rk.w;
            bv.x += rv.x; bv.y += rv.y; bv.z += rv.z; bv.w += rv.w;
        }
        a.x *= inv; a.y *= inv; a.z *= inv; a.w *= inv;
        bv.x *= inv; bv.y *= inv; bv.z *= inv; bv.w *= inv;
        *(float4*)(k_cmp + (size_t)c * (HH * DD) + lane * 4) = a;
        *(float4*)(v_cmp + (size_t)c * (HH * DD) + lane * 4) = bv;
    }
}

// Kernel B1: scores + top-4 selection + o_cmp. grid = T, 4 waves = 4 heads.
// Scores use f32 k_cmp (selection must match reference top_k exactly).
__global__ __launch_bounds__(256) void hstu_cmp_top(
    const float* __restrict__ q, const float* __restrict__ g_cmp,
    const int* __restrict__ offsets, int B,
    const float* __restrict__ k_cmp, const float* __restrict__ v_cmp,
    float* __restrict__ o_cmp, int* __restrict__ sels_out) {
    int t = blockIdx.x;
    int h = threadIdx.x >> 6;
    int lane = threadIdx.x & 63;
    __shared__ __align__(16) float s_lds[HH][16];
    __shared__ __align__(16) float p_lds[HH][16];

    int b = 0;
    while (b + 1 < B && t >= offsets[b + 1]) ++b;
    int p = t - offsets[b];
    int q_blk = p >> 5;
    int base_cmp = 0, totC = 0;
    for (int bb = 0; bb < B; ++bb) {
        int nb = (offsets[bb + 1] - offsets[bb] + BS - 1) >> 5;
        if (bb < b) base_cmp += nb;
        totC += nb;
    }

    // ---- scores: lane=(c4,d4); 4 k-load instrs ----
    int d4 = lane & 15, c4 = lane >> 4;
    float4 qf = *(const float4*)(q + ((size_t)t * HH + h) * DD + d4 * 4);
    float sc_own[4], pc_own[4];
    #pragma unroll
    for (int m = 0; m < 4; ++m) {
        int j = m * 4 + c4;
        int ci = base_cmp + j; if (ci > totC - 1) ci = totC - 1;
        float4 kk = *(const float4*)(k_cmp + (size_t)ci * (HH * DD) + h * DD + d4 * 4);
        float pp = qf.x * kk.x + qf.y * kk.y + qf.z * kk.z + qf.w * kk.w;
        pp += __shfl_xor(pp, 1);
        pp += __shfl_xor(pp, 2);
        pp += __shfl_xor(pp, 4);
        pp += __shfl_xor(pp, 8);
        sc_own[m] = pp * 0.125f;
        pc_own[m] = (j <= q_blk) ? silu_f(sc_own[m]) : 0.f;
    }
    if (d4 == 0) {
        #pragma unroll
        for (int m = 0; m < 4; ++m) {
            s_lds[h][m * 4 + c4] = sc_own[m];
            p_lds[h][m * 4 + c4] = pc_own[m];
        }
    }
    __builtin_amdgcn_wave_barrier();  // same-wave DS write->read ordering

    float sc_[16], pc_[16];
    #pragma unroll
    for (int x = 0; x < 4; ++x) {
        float4 sd = ((const float4*)s_lds[h])[x];
        float4 pd = ((const float4*)p_lds[h])[x];
        sc_[x*4+0] = sd.x; sc_[x*4+1] = sd.y; sc_[x*4+2] = sd.z; sc_[x*4+3] = sd.w;
        pc_[x*4+0] = pd.x; pc_[x*4+1] = pd.y; pc_[x*4+2] = pd.z; pc_[x*4+3] = pd.w;
    }

    // ---- top-4 via rank + ballot (ties -> lowest index; set-equal to lax.top_k) ----
    int j_own = lane >> 2;
    float s_own = sc_[j_own];
    int rank = 0;
    #pragma unroll
    for (int kk = 0; kk < 16; ++kk) {
        bool beats = (kk <= q_blk) && ((sc_[kk] > s_own) || (sc_[kk] == s_own && kk < j_own));
        rank += beats ? 1 : 0;
    }
    bool mine = ((lane & 3) == 0) && (j_own <= q_blk) && (rank < 4);
    unsigned long long msk = __ballot(mine);
    int sel0, sel1, sel2, sel3;
    sel0 = msk ? (int)(__builtin_ctzll(msk) >> 2) : -1; msk &= msk - 1;
    sel1 = msk ? (int)(__builtin_ctzll(msk) >> 2) : -1; msk &= msk - 1;
    sel2 = msk ? (int)(__builtin_ctzll(msk) >> 2) : -1; msk &= msk - 1;
    sel3 = msk ? (int)(__builtin_ctzll(msk) >> 2) : -1;
    if (lane == 0) {
        int4 o4 = make_int4(sel0, sel1, sel2, sel3);
        *(int4*)(sels_out + ((size_t)t * HH + h) * 4) = o4;
    }

    // ---- o_cmp: lane=(c4,d4); 4 v-load instrs + float4 shfl reduce over c4 ----
    float4 facc = make_float4(0.f, 0.f, 0.f, 0.f);
    #pragma unroll
    for (int m = 0; m < 4; ++m) {
        int j = m * 4 + c4;
        int ci = base_cmp + j; if (ci > totC - 1) ci = totC - 1;
        float4 vv = *(const float4*)(v_cmp + (size_t)ci * (HH * DD) + h * DD + d4 * 4);
        float pj = pc_[j];  // 0 for non-causal
        facc.x += pj * vv.x; facc.y += pj * vv.y; facc.z += pj * vv.z; facc.w += pj * vv.w;
    }
    facc.x += __shfl_xor(facc.x, 16); facc.x += __shfl_xor(facc.x, 32);
    facc.y += __shfl_xor(facc.y, 16); facc.y += __shfl_xor(facc.y, 32);
    facc.z += __shfl_xor(facc.z, 16); facc.z += __shfl_xor(facc.z, 32);
    facc.w += __shfl_xor(facc.w, 16); facc.w += __shfl_xor(facc.w, 32);
    if (c4 == 0) {
        float gc = g_cmp[(size_t)t * HH + h];
        float4 o = make_float4(facc.x * gc, facc.y * gc, facc.z * gc, facc.w * gc);
        *(float4*)(o_cmp + ((size_t)t * HH + h) * DD + d4 * 4) = o;
    }
}

// Kernel B2: o_slc from bf16 kb/vb. grid = T*HH, 4 waves = 4 selected blocks.
// lane=(it8,d8): 8 rows/instr x 8 lanes x 16B; 4 k-loads + 4 v-loads per wave.
__global__ __launch_bounds__(256) void hstu_slc(
    const float* __restrict__ q,
    const unsigned short* __restrict__ kb, const unsigned short* __restrict__ vb,
    const float* __restrict__ g_slc, const int* __restrict__ offsets, int B,
    const int* __restrict__ sels_in, float* __restrict__ o_slc) {
    int t = blockIdx.x >> 2, h = blockIdx.x & 3;
    int r = threadIdx.x >> 6;
    int lane = threadIdx.x & 63;
    __shared__ __align__(16) float red_s[4][DD];

    int b = 0;
    while (b + 1 < B && t >= offsets[b + 1]) ++b;
    int seq_start = offsets[b];
    int p = t - seq_start;

    int4 s4 = *(const int4*)(sels_in + ((size_t)t * HH + h) * 4);
    int sel = (r == 0) ? s4.x : (r == 1) ? s4.y : (r == 2) ? s4.z : s4.w;
    int lim = (sel >= 0) ? min(p - sel * BS + 1, BS) : 0;  // >=1 when sel>=0
    int blk_base = seq_start + sel * BS;

    int d8 = lane & 7, it8 = lane >> 3;
    const float* qbase = q + ((size_t)t * HH + h) * DD + d8 * 8;
    float4 q0 = *(const float4*)qbase;
    float4 q1 = *(const float4*)(qbase + 4);

    uint4 kw[4], vw[4];
    int rows[4];
    #pragma unroll
    for (int m = 0; m < 4; ++m) {
        int i = m * 8 + it8;
        int row = t;
        if (sel >= 0) row = blk_base + min(i, lim - 1);
        rows[m] = row;
        kw[m] = *(const uint4*)(kb + ((size_t)row * HH + h) * DD + d8 * 8);
    }
    #pragma unroll
    for (int m = 0; m < 4; ++m)
        vw[m] = *(const uint4*)(vb + ((size_t)rows[m] * HH + h) * DD + d8 * 8);

    float4 accA = make_float4(0.f, 0.f, 0.f, 0.f);
    float4 accB = make_float4(0.f, 0.f, 0.f, 0.f);
    #pragma unroll
    for (int m = 0; m < 4; ++m) {
        int i = m * 8 + it8;
        float pp = q0.x * bflo(kw[m].x) + q0.y * bfhi(kw[m].x)
                 + q0.z * bflo(kw[m].y) + q0.w * bfhi(kw[m].y)
                 + q1.x * bflo(kw[m].z) + q1.y * bfhi(kw[m].z)
                 + q1.z * bflo(kw[m].w) + q1.w * bfhi(kw[m].w);
        pp += __shfl_xor(pp, 1);
        pp += __shfl_xor(pp, 2);
        pp += __shfl_xor(pp, 4);
        float ps = (i < lim) ? silu_f(pp * 0.125f) : 0.f;
        accA.x += ps * bflo(vw[m].x); accA.y += ps * bfhi(vw[m].x);
        accA.z += ps * bflo(vw[m].y); accA.w += ps * bfhi(vw[m].y);
        accB.x += ps * bflo(vw[m].z); accB.y += ps * bfhi(vw[m].z);
        accB.z += ps * bflo(vw[m].w); accB.w += ps * bfhi(vw[m].w);
    }

    // reduce over it8 groups (lane bits 3..5)
    accA.x += __shfl_xor(accA.x, 8); accA.x += __shfl_xor(accA.x, 16); accA.x += __shfl_xor(accA.x, 32);
    accA.y += __shfl_xor(accA.y, 8); accA.y += __shfl_xor(accA.y, 16); accA.y += __shfl_xor(accA.y, 32);
    accA.z += __shfl_xor(accA.z, 8); accA.z += __shfl_xor(accA.z, 16); accA.z += __shfl_xor(accA.z, 32);
    accA.w += __shfl_xor(accA.w, 8); accA.w += __shfl_xor(accA.w, 16); accA.w += __shfl_xor(accA.w, 32);
    accB.x += __shfl_xor(accB.x, 8); accB.x += __shfl_xor(accB.x, 16); accB.x += __shfl_xor(accB.x, 32);
    accB.y += __shfl_xor(accB.y, 8); accB.y += __shfl_xor(accB.y, 16); accB.y += __shfl_xor(accB.y, 32);
    accB.z += __shfl_xor(accB.z, 8); accB.z += __shfl_xor(accB.z, 16); accB.z += __shfl_xor(accB.z, 32);
    accB.w += __shfl_xor(accB.w, 8); accB.w += __shfl_xor(accB.w, 16); accB.w += __shfl_xor(accB.w, 32);

    // cross-wave combine
    if (r != 0 && it8 == 0) {
        *(float4*)&red_s[r][d8 * 8]     = accA;
        *(float4*)&red_s[r][d8 * 8 + 4] = accB;
    }
    __syncthreads();
    if (r == 0 && it8 == 0) {
        #pragma unroll
        for (int g = 1; g < 4; ++g) {
            float4 ra = *(const float4*)&red_s[g][d8 * 8];
            float4 rb = *(const float4*)&red_s[g][d8 * 8 + 4];
            accA.x += ra.x; accA.y += ra.y; accA.z += ra.z; accA.w += ra.w;
            accB.x += rb.x; accB.y += rb.y; accB.z += rb.z; accB.w += rb.w;
        }
        float gs = g_slc[(size_t)t * HH + h];
        accA.x *= gs; accA.y *= gs; accA.z *= gs; accA.w *= gs;
        accB.x *= gs; accB.y *= gs; accB.z *= gs; accB.w *= gs;
        float* ob = o_slc + ((size_t)t * HH + h) * DD + d8 * 8;
        *(float4*)ob = accA;
        *(float4*)(ob + 4) = accB;
    }
}

extern "C" void kernel_launch(void* const* d_in, const int* in_sizes, int n_in,
                              void* d_out, int out_size, void* d_ws, size_t ws_size,
                              hipStream_t stream) {
    const float* q     = (const float*)d_in[0];
    const float* k     = (const float*)d_in[1];
    const float* v     = (const float*)d_in[2];
    const float* g_cmp = (const float*)d_in[3];
    const float* g_slc = (const float*)d_in[4];
    const int*   offs  = (const int*)d_in[5];

    int T = in_sizes[0] / (HH * DD);
    int B = in_sizes[5] - 1;
    int maxC = (T + BS - 1) / BS + B;

    float* k_cmp = (float*)d_ws;
    float* v_cmp = k_cmp + (size_t)maxC * HH * DD;
    int*   sels  = (int*)(v_cmp + (size_t)maxC * HH * DD);
    unsigned short* kb = (unsigned short*)(sels + (size_t)T * HH * 4);
    unsigned short* vb = kb + (size_t)T * HH * DD;
    float* o_cmp = (float*)d_out;
    float* o_slc = (float*)d_out + (size_t)T * HH * DD;

    hipLaunchKernelGGL(hstu_cmp_means, dim3(maxC), dim3(256), 0, stream,
                       k, v, offs, B, k_cmp, v_cmp, kb, vb);
    hipLaunchKernelGGL(hstu_cmp_top, dim3(T), dim3(256), 0, stream,
                       q, g_cmp, offs, B, k_cmp, v_cmp, o_cmp, sels);
    hipLaunchKernelGGL(hstu_slc, dim3(T * HH), dim3(256), 0, stream,
                       q, kb, vb, g_slc, offs, B, sels, o_slc);
}